// Round 4
// baseline (1088.419 us; speedup 1.0000x reference)
//
#include <hip/hip_runtime.h>

typedef _Float16 half8 __attribute__((ext_vector_type(8)));
typedef _Float16 half4v __attribute__((ext_vector_type(4)));
typedef _Float16 half2v __attribute__((ext_vector_type(2)));
typedef float floatx4 __attribute__((ext_vector_type(4)));

namespace {
constexpr int RES = 256;
constexpr float SCALE_ = 0.17677669529663687f;  // 1/sqrt(32)
constexpr size_t WT_BYTES = 294912;             // fp16 weights region in ws
constexpr size_t NPX = 131072;                  // pixels per 2-batch chunk
constexpr size_t QK_BYTES = NPX * 384 * 2;      // 100,663,296
constexpr size_t V_BYTES  = NPX * 192 * 2;      //  50,331,648
constexpr size_t O_BYTES  = NPX * 192 * 2;      //  50,331,648
}

// XOR-swizzled byte offset into the 64x64 fp16 P tile (128 B per row).
__device__ __forceinline__ int st_off(int r, int c) {
  return (r * 128 + c * 2) ^ ((r & 7) << 4);
}

// ---- prep: transpose+convert weights to fp16 in workspace.
__global__ void prep_weights(const float* __restrict__ qkv_w,
                             const float* __restrict__ proj_w,
                             _Float16* __restrict__ qkv_wt,
                             _Float16* __restrict__ proj_wt) {
  const int col = blockIdx.x;
  const int k = threadIdx.x;  // 192
  if (col < 576) {
    qkv_wt[col * 192 + k] = (_Float16)qkv_w[(size_t)k * 576 + col];
  } else {
    const int c = col - 576;
    proj_wt[c * 192 + k] = (_Float16)proj_w[(size_t)k * 192 + c];
  }
}

// ============================================================================
// K_A: QKV GEMM, 64 w-contiguous pixels per block. Outputs (rolled py order):
//   qk[py][384] fp16  (q pre-scaled | k)         -- half8 staged stores
//   vpl[d][py]  fp16  (V channel-planar)         -- half4 staged stores
// All global stores go through LDS so each instruction writes wide
// contiguous segments (384 B / 128 B) instead of 2-B scalar scatter.
// ============================================================================
__global__ __launch_bounds__(512, 8)
void qkv_gemm(const float* __restrict__ x, const _Float16* __restrict__ qkv_wt,
              const float* __restrict__ qkv_b, _Float16* __restrict__ qk,
              _Float16* __restrict__ vpl, const int b_off) {
  __shared__ _Float16 pool[13056];  // xs[64][200] -> os[64][200] / osT[192][68]
  const int pid = blockIdx.x;
  const int w0 = (pid & 3) * 64;
  const int h = (pid >> 2) & (RES - 1);
  const int bb = pid >> 10;
  const int tid = threadIdx.x;

  // stage x -> xs[px][ch]
#pragma unroll
  for (int t = 0; t < 3; ++t) {
    const int f = tid + t * 512;
    const int c2 = (f & 31) + 32 * (f >> 9);
    const int wg = (f >> 5) & 15;
    const size_t base =
        (((size_t)(b_off + bb) * 192 + c2 * 2) * RES + h) * RES + w0 + wg * 4;
    const float4 va = *reinterpret_cast<const float4*>(x + base);
    const float4 vb = *reinterpret_cast<const float4*>(x + base + (size_t)RES * RES);
    const int tok = wg * 4;
    half2v p;
    p[0] = (_Float16)va.x; p[1] = (_Float16)vb.x;
    *(half2v*)&pool[(tok + 0) * 200 + c2 * 2] = p;
    p[0] = (_Float16)va.y; p[1] = (_Float16)vb.y;
    *(half2v*)&pool[(tok + 1) * 200 + c2 * 2] = p;
    p[0] = (_Float16)va.z; p[1] = (_Float16)vb.z;
    *(half2v*)&pool[(tok + 2) * 200 + c2 * 2] = p;
    p[0] = (_Float16)va.w; p[1] = (_Float16)vb.w;
    *(half2v*)&pool[(tok + 3) * 200 + c2 * 2] = p;
  }
  __syncthreads();

  const int wv = tid >> 6, lane = tid & 63;
  const int ln = lane & 15, quad = lane >> 4;
  const int mt = wv >> 1, hf = wv & 1;

  half8 af[6];
#pragma unroll
  for (int k = 0; k < 6; ++k)
    af[k] = *(const half8*)&pool[(mt * 16 + ln) * 200 + k * 32 + quad * 8];
  __syncthreads();  // xs dead; pool becomes the output staging buffer

  const int rh = (h + RES - 4) & (RES - 1);
  const int rowbase = (bb * RES + rh) * RES;

  for (int cc = 0; cc < 3; ++cc) {  // col chunks: q, k, v
    for (int i = 0; i < 6; ++i) {
      const int c_l = (hf * 6 + i) * 16;     // 0..176
      const int colb = cc * 192 + c_l;
      floatx4 acc = {0.f, 0.f, 0.f, 0.f};
#pragma unroll
      for (int k = 0; k < 6; ++k) {
        const half8 bf =
            *(const half8*)(qkv_wt + (size_t)(colb + ln) * 192 + k * 32 + quad * 8);
        acc = __builtin_amdgcn_mfma_f32_16x16x32_f16(af[k], bf, acc, 0, 0, 0);
      }
      const float bias = qkv_b[colb + ln];
      const float scl = (cc == 0) ? SCALE_ : 1.0f;
      const int tok0 = mt * 16 + quad * 4;
      if (cc < 2) {
#pragma unroll
        for (int j = 0; j < 4; ++j)
          pool[(tok0 + j) * 200 + c_l + ln] = (_Float16)((acc[j] + bias) * scl);
      } else {
        half4v p;
#pragma unroll
        for (int j = 0; j < 4; ++j) p[j] = (_Float16)(acc[j] + bias);
        *(half4v*)&pool[(c_l + ln) * 68 + tok0] = p;  // transposed [d][px]
      }
    }
    __syncthreads();
    if (cc < 2) {
      // 64 px x 384 B contiguous rows
#pragma unroll
      for (int p = 0; p < 3; ++p) {
        const int idx = tid + p * 512;            // 0..1535
        const int px = idx / 24, off = idx - px * 24;
        const half8 v = *(const half8*)&pool[px * 200 + off * 8];
        const int rw = (w0 + px + RES - 4) & (RES - 1);
        *(half8*)&qk[(size_t)(rowbase + rw) * 384 + cc * 192 + off * 8] = v;
      }
    } else {
      // 192 d-planes x 128 B contiguous runs
#pragma unroll
      for (int p = 0; p < 6; ++p) {
        const int idx = tid + p * 512;            // 0..3071
        const int d = idx >> 4, g4 = idx & 15;
        const half4v v = *(const half4v*)&pool[d * 68 + g4 * 4];
        const int rw = (w0 + g4 * 4 + RES - 4) & (RES - 1);
        *(half4v*)&vpl[(size_t)d * NPX + rowbase + rw] = v;
      }
    }
    __syncthreads();
  }
}

// ============================================================================
// K_B: window attention. One 64-lane wave per (window, head). No barriers.
// q/k fragments: direct 16-B loads from qk[py][384]. V fragments: direct
// 16-B loads from the planar layout (no LDS transpose). P lives in an
// XOR-swizzled 8 KB LDS tile. Softmax in-register via 16-lane shuffles.
// ============================================================================
__global__ __launch_bounds__(64)
void win_attn(const _Float16* __restrict__ qk, const _Float16* __restrict__ vpl,
              _Float16* __restrict__ O) {
  __shared__ _Float16 stp[4096];  // swizzled P [64][64], 8 KB
  char* sb = (char*)stp;
  const int wn = blockIdx.x, hd = blockIdx.y;
  const int bb = wn >> 10, wh = (wn >> 5) & 31, ww = wn & 31;
  const int l = threadIdx.x, ln = l & 15, quad = l >> 4;
  const int base = (bb * RES + wh * 8) * RES + ww * 8;  // py of token 0

  const int p0 = base + (ln >> 3) * RES + (ln & 7);
  const _Float16* qp = qk + (size_t)p0 * 384 + hd * 32 + quad * 8;
  half8 qf[4], kf[4];
#pragma unroll
  for (int s = 0; s < 4; ++s) {
    qf[s] = *(const half8*)(qp + (size_t)s * (512 * 384));
    kf[s] = *(const half8*)(qp + (size_t)s * (512 * 384) + 192);
  }
  // V B-fragments direct from planar: B[k=quad*8+j][n=ln]
  half8 bv[2][2];
#pragma unroll
  for (int pnt = 0; pnt < 2; ++pnt)
#pragma unroll
    for (int ks = 0; ks < 2; ++ks)
      bv[pnt][ks] = *(const half8*)(vpl +
          (size_t)(hd * 32 + pnt * 16 + ln) * NPX + base + (ks * 4 + quad) * RES);

  // scores + in-register softmax; P (pre-divided) -> swizzled LDS
#pragma unroll
  for (int smt = 0; smt < 4; ++smt) {
    floatx4 sc[4];
#pragma unroll
    for (int snt = 0; snt < 4; ++snt) {
      floatx4 z = {0.f, 0.f, 0.f, 0.f};
      sc[snt] = __builtin_amdgcn_mfma_f32_16x16x32_f16(qf[smt], kf[snt], z, 0, 0, 0);
    }
#pragma unroll
    for (int j = 0; j < 4; ++j) {
      float m = fmaxf(fmaxf(sc[0][j], sc[1][j]), fmaxf(sc[2][j], sc[3][j]));
      m = fmaxf(m, __shfl_xor(m, 1));
      m = fmaxf(m, __shfl_xor(m, 2));
      m = fmaxf(m, __shfl_xor(m, 4));
      m = fmaxf(m, __shfl_xor(m, 8));
      const float e0 = __expf(sc[0][j] - m);
      const float e1 = __expf(sc[1][j] - m);
      const float e2 = __expf(sc[2][j] - m);
      const float e3 = __expf(sc[3][j] - m);
      float s = e0 + e1 + e2 + e3;
      s += __shfl_xor(s, 1);
      s += __shfl_xor(s, 2);
      s += __shfl_xor(s, 4);
      s += __shfl_xor(s, 8);
      const float inv = 1.0f / s;
      const int r = smt * 16 + quad * 4 + j;
      *(_Float16*)(sb + st_off(r, ln))      = (_Float16)(e0 * inv);
      *(_Float16*)(sb + st_off(r, 16 + ln)) = (_Float16)(e1 * inv);
      *(_Float16*)(sb + st_off(r, 32 + ln)) = (_Float16)(e2 * inv);
      *(_Float16*)(sb + st_off(r, 48 + ln)) = (_Float16)(e3 * inv);
    }
  }

  // O = P @ V
#pragma unroll
  for (int pmt = 0; pmt < 4; ++pmt) {
    const int px = pmt * 16 + ln;
    const half8 ap0 = *(const half8*)(sb + st_off(px, quad * 8));
    const half8 ap1 = *(const half8*)(sb + st_off(px, 32 + quad * 8));
    const int pyr = base + (pmt * 2 + (quad >> 1)) * RES + (quad & 1) * 4;
#pragma unroll
    for (int pnt = 0; pnt < 2; ++pnt) {
      floatx4 acc = {0.f, 0.f, 0.f, 0.f};
      acc = __builtin_amdgcn_mfma_f32_16x16x32_f16(ap0, bv[pnt][0], acc, 0, 0, 0);
      acc = __builtin_amdgcn_mfma_f32_16x16x32_f16(ap1, bv[pnt][1], acc, 0, 0, 0);
#pragma unroll
      for (int j = 0; j < 4; ++j)
        O[(size_t)(pyr + j) * 192 + hd * 32 + pnt * 16 + ln] = (_Float16)acc[j];
    }
  }
}

// ============================================================================
// K_C: projection GEMM + un-roll. 64 px per block, 4 waves, wave-private LDS
// staging (zero barriers) -> float4 stores, 256-B contiguous per c-plane.
// ============================================================================
__global__ __launch_bounds__(256, 6)
void proj_gemm(const _Float16* __restrict__ O, const _Float16* __restrict__ proj_wt,
               const float* __restrict__ proj_b, float* __restrict__ out,
               const int b_off) {
  __shared__ float ls[4][16][100];  // 25.6 KB, wave-private slabs
  const int pid = ((int)blockIdx.x & 7) * 256 + ((int)blockIdx.x >> 3);
  const int rw0 = (pid & 3) * 64;
  const int rh = (pid >> 2) & (RES - 1);
  const int bb = pid >> 10;
  const int tid = threadIdx.x;
  const int wv = tid >> 6, lane = tid & 63;
  const int ln = lane & 15, quad = lane >> 4;
  const int py0 = (bb * RES + rh) * RES + rw0 + wv * 16;

  half8 af[6];
#pragma unroll
  for (int k = 0; k < 6; ++k)
    af[k] = *(const half8*)(O + (size_t)(py0 + ln) * 192 + k * 32 + quad * 8);

  const int h = (rh + 4) & (RES - 1);
  const size_t outb =
      ((size_t)(b_off + bb) * 192) * (RES * RES) + (size_t)h * RES;
  for (int hh = 0; hh < 2; ++hh) {  // two 96-col halves
#pragma unroll
    for (int i = 0; i < 6; ++i) {
      const int c = (hh * 6 + i) * 16 + ln;
      floatx4 acc = {0.f, 0.f, 0.f, 0.f};
#pragma unroll
      for (int k = 0; k < 6; ++k) {
        const half8 bf =
            *(const half8*)(proj_wt + (size_t)c * 192 + k * 32 + quad * 8);
        acc = __builtin_amdgcn_mfma_f32_16x16x32_f16(af[k], bf, acc, 0, 0, 0);
      }
      const float bias = proj_b[c];
#pragma unroll
      for (int j = 0; j < 4; ++j)
        ls[wv][quad * 4 + j][i * 16 + ln] = acc[j] + bias;
    }
    // wave-synchronous LDS->global, fully coalesced
#pragma unroll
    for (int s = 0; s < 6; ++s) {
      const int idx = lane + s * 64;           // 0..383
      const int cl = idx >> 2, g = idx & 3;
      float4 v;
      v.x = ls[wv][g * 4 + 0][cl];
      v.y = ls[wv][g * 4 + 1][cl];
      v.z = ls[wv][g * 4 + 2][cl];
      v.w = ls[wv][g * 4 + 3][cl];
      const int c = hh * 96 + cl;
      const int wout = (rw0 + wv * 16 + g * 4 + 4) & (RES - 1);
      *reinterpret_cast<float4*>(out + outb + (size_t)c * (RES * RES) + wout) = v;
    }
  }
}

// ============================================================================
// Fallback: fused single-kernel path (only if workspace too small).
// ============================================================================
__global__ __launch_bounds__(512, 6)
void win_attn_fused(const float* __restrict__ x,
                    const _Float16* __restrict__ qkv_wt,
                    const float* __restrict__ qkv_b,
                    const _Float16* __restrict__ proj_wt,
                    const float* __restrict__ proj_b,
                    float* __restrict__ out) {
  __shared__ _Float16 xs[64][200];
  __shared__ _Float16 qB[64][40];
  __shared__ _Float16 kB[64][40];
  __shared__ _Float16 vT[32][72];
  __shared__ _Float16 st[64][80];
  __shared__ float rowred[64];

  const int wid = ((int)blockIdx.x & 7) * 512 + ((int)blockIdx.x >> 3);
  const int b = wid >> 10, wh = (wid >> 5) & 31, ww = wid & 31;
  const int wv = threadIdx.x >> 6;
  const int lane = threadIdx.x & 63;
  const int ln = lane & 15;
  const int quad = lane >> 4;
  const int mt = wv >> 1, ng = wv & 1;

#pragma unroll
  for (int t = 0; t < 3; ++t) {
    const int f = threadIdx.x + t * 512;
    const int c2 = (f & 31) + 32 * (f >> 9);
    const int tg = (f >> 5) & 15;
    const int r = tg >> 1;
    const int cw = (tg & 1) * 4;
    const int h = (wh * 8 + r + 4) & (RES - 1);
    const int w0 = (ww * 8 + cw + 4) & (RES - 1);
    const size_t base = (((size_t)b * 192 + c2 * 2) * RES + h) * RES + w0;
    const float4 va = *reinterpret_cast<const float4*>(x + base);
    const float4 vb = *reinterpret_cast<const float4*>(x + base + (size_t)RES * RES);
    const int tok = tg * 4;
    half2v p;
    p[0] = (_Float16)va.x; p[1] = (_Float16)vb.x;
    *(half2v*)&xs[tok + 0][c2 * 2] = p;
    p[0] = (_Float16)va.y; p[1] = (_Float16)vb.y;
    *(half2v*)&xs[tok + 1][c2 * 2] = p;
    p[0] = (_Float16)va.z; p[1] = (_Float16)vb.z;
    *(half2v*)&xs[tok + 2][c2 * 2] = p;
    p[0] = (_Float16)va.w; p[1] = (_Float16)vb.w;
    *(half2v*)&xs[tok + 3][c2 * 2] = p;
  }
  __syncthreads();

  floatx4 acc6[6];
#pragma unroll
  for (int i = 0; i < 6; ++i) acc6[i] = (floatx4){0.f, 0.f, 0.f, 0.f};

  for (int hd = 0; hd < 6; ++hd) {
    {
      int colb[3];
#pragma unroll
      for (int i = 0; i < 3; ++i) {
        const int nt = ng * 3 + i;
        colb[i] = (nt >> 1) * 192 + hd * 32 + (nt & 1) * 16;
      }
      floatx4 acc[3];
#pragma unroll
      for (int i = 0; i < 3; ++i) acc[i] = (floatx4){0.f, 0.f, 0.f, 0.f};
#pragma unroll
      for (int k = 0; k < 6; ++k) {
        const half8 af = *(const half8*)&xs[mt * 16 + ln][k * 32 + quad * 8];
#pragma unroll
        for (int i = 0; i < 3; ++i) {
          const half8 bf = *(const half8*)(qkv_wt +
              (size_t)(colb[i] + ln) * 192 + k * 32 + quad * 8);
          acc[i] = __builtin_amdgcn_mfma_f32_16x16x32_f16(af, bf, acc[i], 0, 0, 0);
        }
      }
#pragma unroll
      for (int i = 0; i < 3; ++i) {
        const int nt = ng * 3 + i;
        const int sec = nt >> 1;
        const float bias = qkv_b[colb[i] + ln];
        const int tok0 = mt * 16 + quad * 4;
        const int d = (nt & 1) * 16 + ln;
        if (sec == 0) {
#pragma unroll
          for (int j = 0; j < 4; ++j)
            qB[tok0 + j][d] = (_Float16)((acc[i][j] + bias) * SCALE_);
        } else if (sec == 1) {
#pragma unroll
          for (int j = 0; j < 4; ++j)
            kB[tok0 + j][d] = (_Float16)(acc[i][j] + bias);
        } else {
#pragma unroll
          for (int j = 0; j < 4; ++j)
            vT[d][tok0 + j] = (_Float16)(acc[i][j] + bias);
        }
      }
    }
    __syncthreads();

#pragma unroll
    for (int i = 0; i < 2; ++i) {
      const int t = wv * 2 + i;
      const int smt = t >> 2, snt = t & 3;
      const half8 aq = *(const half8*)&qB[smt * 16 + ln][quad * 8];
      const half8 bk = *(const half8*)&kB[snt * 16 + ln][quad * 8];
      floatx4 acc = {0.f, 0.f, 0.f, 0.f};
      acc = __builtin_amdgcn_mfma_f32_16x16x32_f16(aq, bk, acc, 0, 0, 0);
      const int r0 = smt * 16 + quad * 4;
#pragma unroll
      for (int j = 0; j < 4; ++j)
        st[r0 + j][snt * 16 + ln] = (_Float16)acc[j];
    }
    __syncthreads();

    {
      const int row = threadIdx.x >> 3;
      const int sl = threadIdx.x & 7;
      const half8 hv = *(const half8*)&st[row][sl * 8];
      float m = -3.0e38f;
#pragma unroll
      for (int j = 0; j < 8; ++j) m = fmaxf(m, (float)hv[j]);
      m = fmaxf(m, __shfl_xor(m, 1));
      m = fmaxf(m, __shfl_xor(m, 2));
      m = fmaxf(m, __shfl_xor(m, 4));
      float s = 0.f;
      half8 ev;
#pragma unroll
      for (int j = 0; j < 8; ++j) {
        const float e = __expf((float)hv[j] - m);
        s += e;
        ev[j] = (_Float16)e;
      }
      *(half8*)&st[row][sl * 8] = ev;
      s += __shfl_xor(s, 1);
      s += __shfl_xor(s, 2);
      s += __shfl_xor(s, 4);
      if (sl == 0) rowred[row] = 1.0f / s;
    }
    __syncthreads();

    {
      const int pmt = wv >> 1, pnt = wv & 1;
      floatx4 acc = {0.f, 0.f, 0.f, 0.f};
#pragma unroll
      for (int ks = 0; ks < 2; ++ks) {
        const half8 ap = *(const half8*)&st[pmt * 16 + ln][ks * 32 + quad * 8];
        const half8 bvv = *(const half8*)&vT[pnt * 16 + ln][ks * 32 + quad * 8];
        acc = __builtin_amdgcn_mfma_f32_16x16x32_f16(ap, bvv, acc, 0, 0, 0);
      }
      const int tok0 = pmt * 16 + quad * 4;
      const int d = pnt * 16 + ln;
#pragma unroll
      for (int j = 0; j < 4; ++j)
        qB[tok0 + j][d] = (_Float16)(acc[j] * rowred[tok0 + j]);
    }
    __syncthreads();

    {
      const half8 af = *(const half8*)&qB[mt * 16 + ln][quad * 8];
#pragma unroll
      for (int i = 0; i < 6; ++i) {
        const int c = (ng * 6 + i) * 16 + ln;
        const half8 bf = *(const half8*)(proj_wt +
            (size_t)c * 192 + hd * 32 + quad * 8);
        acc6[i] = __builtin_amdgcn_mfma_f32_16x16x32_f16(af, bf, acc6[i], 0, 0, 0);
      }
    }
    __syncthreads();
  }

  {
#pragma unroll
    for (int i = 0; i < 6; ++i) {
      const int c = (ng * 6 + i) * 16 + ln;
      const float bias = proj_b[c];
      const int tok0 = mt * 16 + quad * 4;
      const int r = tok0 >> 3, cw = tok0 & 7;
      const int h = (wh * 8 + r + 4) & (RES - 1);
      const int w0 = (ww * 8 + cw + 4) & (RES - 1);
      float4 vv;
      vv.x = acc6[i][0] + bias;
      vv.y = acc6[i][1] + bias;
      vv.z = acc6[i][2] + bias;
      vv.w = acc6[i][3] + bias;
      *reinterpret_cast<float4*>(
          out + (((size_t)b * 192 + c) * RES + h) * RES + w0) = vv;
    }
  }
}

extern "C" void kernel_launch(void* const* d_in, const int* in_sizes, int n_in,
                              void* d_out, int out_size, void* d_ws, size_t ws_size,
                              hipStream_t stream) {
  (void)in_sizes; (void)n_in; (void)out_size;
  const float* x      = (const float*)d_in[0];
  const float* qkv_w  = (const float*)d_in[1];
  const float* qkv_b  = (const float*)d_in[2];
  const float* proj_w = (const float*)d_in[3];
  const float* proj_b = (const float*)d_in[4];
  float* out = (float*)d_out;

  _Float16* qkv_wt  = (_Float16*)d_ws;              // 576*192 halfs
  _Float16* proj_wt = qkv_wt + 576 * 192;           // 192*192 halfs

  prep_weights<<<768, 192, 0, stream>>>(qkv_w, proj_w, qkv_wt, proj_wt);

  if (ws_size >= WT_BYTES + QK_BYTES + V_BYTES + O_BYTES) {
    _Float16* qk  = (_Float16*)((char*)d_ws + WT_BYTES);
    _Float16* vpl = (_Float16*)((char*)d_ws + WT_BYTES + QK_BYTES);
    _Float16* Obuf = (_Float16*)((char*)d_ws + WT_BYTES + QK_BYTES + V_BYTES);
    for (int c = 0; c < 2; ++c) {
      const int b_off = c * 2;  // two batches per chunk
      qkv_gemm<<<2048, 512, 0, stream>>>(x, qkv_wt, qkv_b, qk, vpl, b_off);
      win_attn<<<dim3(2048, 6), 64, 0, stream>>>(qk, vpl, Obuf);
      proj_gemm<<<2048, 256, 0, stream>>>(Obuf, proj_wt, proj_b, out, b_off);
    }
  } else {
    win_attn_fused<<<4096, 512, 0, stream>>>(x, qkv_wt, qkv_b, proj_wt,
                                             proj_b, out);
  }
}

// Round 5
// 823.838 us; speedup vs baseline: 1.3212x; 1.3212x over previous
//
#include <hip/hip_runtime.h>

typedef _Float16 half8 __attribute__((ext_vector_type(8)));
typedef _Float16 half4v __attribute__((ext_vector_type(4)));
typedef _Float16 half2v __attribute__((ext_vector_type(2)));
typedef float floatx4 __attribute__((ext_vector_type(4)));

namespace {
constexpr int RES = 256;
constexpr float SCALE_ = 0.17677669529663687f;  // 1/sqrt(32)
// Packed-fragment weights: qkv 36 ntiles, proj 12 ntiles; each ntile = 6
// k-frags x 64 lanes x 8 halfs.
constexpr int QPK_HALFS = 36 * 6 * 64 * 8;      // 110592
constexpr int PPK_HALFS = 12 * 6 * 64 * 8;      //  36864
constexpr size_t WT_BYTES = (QPK_HALFS + PPK_HALFS) * 2;  // 294912
constexpr size_t NPX = 131072;                  // pixels per 2-batch chunk
constexpr size_t QK_BYTES = NPX * 384 * 2;      // 100,663,296
constexpr size_t V_BYTES  = NPX * 192 * 2;      //  50,331,648
constexpr size_t O_BYTES  = NPX * 192 * 2;      //  50,331,648
}

// XOR-swizzled byte offset into the 64x64 fp16 P tile (128 B per row).
__device__ __forceinline__ int st_off(int r, int c) {
  return (r * 128 + c * 2) ^ ((r & 7) << 4);
}

// ---- prep: pack weights into MFMA B-fragment order (fp16).
// pk[((nt*6 + k)*64 + lane)*8 + e] = W[(k*32 + (lane>>4)*8 + e)*ncol + nt*16 + (lane&15)]
// so a wave's B-fragment load is ONE contiguous 1-KB segment.
__global__ void prep_pack(const float* __restrict__ qkv_w,
                          const float* __restrict__ proj_w,
                          _Float16* __restrict__ qpk,
                          _Float16* __restrict__ ppk) {
  const int idx = blockIdx.x * 256 + threadIdx.x;  // 0..18431
  const float* W;
  _Float16* dst;
  int ncol, base;
  if (idx < 13824) {            // 36*6*64
    W = qkv_w; dst = qpk; ncol = 576; base = idx;
  } else {
    W = proj_w; dst = ppk; ncol = 192; base = idx - 13824;
  }
  const int lane = base & 63;
  const int kk = (base >> 6) % 6;
  const int nt = base / 384;
  const int col = nt * 16 + (lane & 15);
  const int krow = kk * 32 + (lane >> 4) * 8;
  half8 v;
#pragma unroll
  for (int e = 0; e < 8; ++e) v[e] = (_Float16)W[(size_t)(krow + e) * ncol + col];
  *(half8*)(dst + (size_t)base * 8) = v;
}

// ============================================================================
// K_A: QKV GEMM, 64 w-contiguous pixels per block. All global loads are
// contiguous-segment: x staged as 4x256-B segments per wave-load (lanes along
// w within one plane); weight fragments from the packed layout (1 KB contig).
// Outputs (rolled py order): qk[py][384] (q pre-scaled | k), vpl[d][py].
// Stores staged through LDS (wide contiguous segments, proven round 4).
// ============================================================================
__global__ __launch_bounds__(512, 8)
void qkv_gemm(const float* __restrict__ x, const _Float16* __restrict__ qpk,
              const float* __restrict__ qkv_b, _Float16* __restrict__ qk,
              _Float16* __restrict__ vpl, const int b_off) {
  __shared__ _Float16 pool[13056];  // xs[64][200] -> os[64][200] / osT[192][68]
  const int pid = blockIdx.x;
  const int w0 = (pid & 3) * 64;
  const int h = (pid >> 2) & (RES - 1);
  const int bb = pid >> 10;
  const int tid = threadIdx.x;

  // stage x -> pool[px][c]; per wave-load: 4 planes x 256 B contiguous.
#pragma unroll
  for (int t = 0; t < 3; ++t) {
    const int idx = tid + t * 512;          // 0..1535
    const int w4 = idx & 15;                // float4 group (4 px along w)
    const int c2 = idx >> 4;                // plane PAIR 0..95
    const size_t base =
        (((size_t)(b_off + bb) * 192 + c2 * 2) * RES + h) * RES + w0 + w4 * 4;
    const float4 va = *reinterpret_cast<const float4*>(x + base);
    const float4 vb = *reinterpret_cast<const float4*>(x + base + (size_t)RES * RES);
    half2v p;
    p[0] = (_Float16)va.x; p[1] = (_Float16)vb.x;
    *(half2v*)&pool[(w4 * 4 + 0) * 200 + c2 * 2] = p;
    p[0] = (_Float16)va.y; p[1] = (_Float16)vb.y;
    *(half2v*)&pool[(w4 * 4 + 1) * 200 + c2 * 2] = p;
    p[0] = (_Float16)va.z; p[1] = (_Float16)vb.z;
    *(half2v*)&pool[(w4 * 4 + 2) * 200 + c2 * 2] = p;
    p[0] = (_Float16)va.w; p[1] = (_Float16)vb.w;
    *(half2v*)&pool[(w4 * 4 + 3) * 200 + c2 * 2] = p;
  }
  __syncthreads();

  const int wv = tid >> 6, lane = tid & 63;
  const int ln = lane & 15, quad = lane >> 4;
  const int mt = wv >> 1, hf = wv & 1;

  half8 af[6];
#pragma unroll
  for (int k = 0; k < 6; ++k)
    af[k] = *(const half8*)&pool[(mt * 16 + ln) * 200 + k * 32 + quad * 8];
  __syncthreads();  // xs dead; pool becomes the output staging buffer

  const int rh = (h + RES - 4) & (RES - 1);
  const int rowbase = (bb * RES + rh) * RES;

  for (int cc = 0; cc < 3; ++cc) {  // col chunks: q, k, v
    for (int i = 0; i < 6; ++i) {
      const int c_l = (hf * 6 + i) * 16;             // 0..176 local col
      const int ntg = cc * 12 + hf * 6 + i;          // global 16-col tile
      const _Float16* bp = qpk + (size_t)ntg * 3072 + lane * 8;
      floatx4 acc = {0.f, 0.f, 0.f, 0.f};
#pragma unroll
      for (int k = 0; k < 6; ++k) {
        const half8 bf = *(const half8*)(bp + k * 512);  // contiguous 1 KB/wave
        acc = __builtin_amdgcn_mfma_f32_16x16x32_f16(af[k], bf, acc, 0, 0, 0);
      }
      const float bias = qkv_b[cc * 192 + c_l + ln];
      const float scl = (cc == 0) ? SCALE_ : 1.0f;
      const int tok0 = mt * 16 + quad * 4;
      if (cc < 2) {
#pragma unroll
        for (int j = 0; j < 4; ++j)
          pool[(tok0 + j) * 200 + c_l + ln] = (_Float16)((acc[j] + bias) * scl);
      } else {
        half4v p;
#pragma unroll
        for (int j = 0; j < 4; ++j) p[j] = (_Float16)(acc[j] + bias);
        *(half4v*)&pool[(c_l + ln) * 68 + tok0] = p;  // transposed [d][px]
      }
    }
    __syncthreads();
    if (cc < 2) {
      // 64 px x 384 B contiguous rows
#pragma unroll
      for (int p = 0; p < 3; ++p) {
        const int idx = tid + p * 512;            // 0..1535
        const int px = idx / 24, off = idx - px * 24;
        const half8 v = *(const half8*)&pool[px * 200 + off * 8];
        const int rw = (w0 + px + RES - 4) & (RES - 1);
        *(half8*)&qk[(size_t)(rowbase + rw) * 384 + cc * 192 + off * 8] = v;
      }
    } else {
      // 192 d-planes x 128 B contiguous runs
#pragma unroll
      for (int p = 0; p < 6; ++p) {
        const int idx = tid + p * 512;            // 0..3071
        const int d = idx >> 4, g4 = idx & 15;
        const half4v v = *(const half4v*)&pool[d * 68 + g4 * 4];
        const int rw = (w0 + g4 * 4 + RES - 4) & (RES - 1);
        *(half4v*)&vpl[(size_t)d * NPX + rowbase + rw] = v;
      }
    }
    __syncthreads();
  }
}

// ============================================================================
// K_B: window attention. One 64-lane wave per (window, head). No barriers.
// (unchanged from round 4)
// ============================================================================
__global__ __launch_bounds__(64)
void win_attn(const _Float16* __restrict__ qk, const _Float16* __restrict__ vpl,
              _Float16* __restrict__ O) {
  __shared__ _Float16 stp[4096];  // swizzled P [64][64], 8 KB
  char* sb = (char*)stp;
  const int wn = blockIdx.x, hd = blockIdx.y;
  const int bb = wn >> 10, wh = (wn >> 5) & 31, ww = wn & 31;
  const int l = threadIdx.x, ln = l & 15, quad = l >> 4;
  const int base = (bb * RES + wh * 8) * RES + ww * 8;  // py of token 0

  const int p0 = base + (ln >> 3) * RES + (ln & 7);
  const _Float16* qp = qk + (size_t)p0 * 384 + hd * 32 + quad * 8;
  half8 qf[4], kf[4];
#pragma unroll
  for (int s = 0; s < 4; ++s) {
    qf[s] = *(const half8*)(qp + (size_t)s * (512 * 384));
    kf[s] = *(const half8*)(qp + (size_t)s * (512 * 384) + 192);
  }
  // V B-fragments direct from planar: B[k=quad*8+j][n=ln]
  half8 bv[2][2];
#pragma unroll
  for (int pnt = 0; pnt < 2; ++pnt)
#pragma unroll
    for (int ks = 0; ks < 2; ++ks)
      bv[pnt][ks] = *(const half8*)(vpl +
          (size_t)(hd * 32 + pnt * 16 + ln) * NPX + base + (ks * 4 + quad) * RES);

  // scores + in-register softmax; P (pre-divided) -> swizzled LDS
#pragma unroll
  for (int smt = 0; smt < 4; ++smt) {
    floatx4 sc[4];
#pragma unroll
    for (int snt = 0; snt < 4; ++snt) {
      floatx4 z = {0.f, 0.f, 0.f, 0.f};
      sc[snt] = __builtin_amdgcn_mfma_f32_16x16x32_f16(qf[smt], kf[snt], z, 0, 0, 0);
    }
#pragma unroll
    for (int j = 0; j < 4; ++j) {
      float m = fmaxf(fmaxf(sc[0][j], sc[1][j]), fmaxf(sc[2][j], sc[3][j]));
      m = fmaxf(m, __shfl_xor(m, 1));
      m = fmaxf(m, __shfl_xor(m, 2));
      m = fmaxf(m, __shfl_xor(m, 4));
      m = fmaxf(m, __shfl_xor(m, 8));
      const float e0 = __expf(sc[0][j] - m);
      const float e1 = __expf(sc[1][j] - m);
      const float e2 = __expf(sc[2][j] - m);
      const float e3 = __expf(sc[3][j] - m);
      float s = e0 + e1 + e2 + e3;
      s += __shfl_xor(s, 1);
      s += __shfl_xor(s, 2);
      s += __shfl_xor(s, 4);
      s += __shfl_xor(s, 8);
      const float inv = 1.0f / s;
      const int r = smt * 16 + quad * 4 + j;
      *(_Float16*)(sb + st_off(r, ln))      = (_Float16)(e0 * inv);
      *(_Float16*)(sb + st_off(r, 16 + ln)) = (_Float16)(e1 * inv);
      *(_Float16*)(sb + st_off(r, 32 + ln)) = (_Float16)(e2 * inv);
      *(_Float16*)(sb + st_off(r, 48 + ln)) = (_Float16)(e3 * inv);
    }
  }

  // O = P @ V
#pragma unroll
  for (int pmt = 0; pmt < 4; ++pmt) {
    const int px = pmt * 16 + ln;
    const half8 ap0 = *(const half8*)(sb + st_off(px, quad * 8));
    const half8 ap1 = *(const half8*)(sb + st_off(px, 32 + quad * 8));
    const int pyr = base + (pmt * 2 + (quad >> 1)) * RES + (quad & 1) * 4;
#pragma unroll
    for (int pnt = 0; pnt < 2; ++pnt) {
      floatx4 acc = {0.f, 0.f, 0.f, 0.f};
      acc = __builtin_amdgcn_mfma_f32_16x16x32_f16(ap0, bv[pnt][0], acc, 0, 0, 0);
      acc = __builtin_amdgcn_mfma_f32_16x16x32_f16(ap1, bv[pnt][1], acc, 0, 0, 0);
#pragma unroll
      for (int j = 0; j < 4; ++j)
        O[(size_t)(pyr + j) * 192 + hd * 32 + pnt * 16 + ln] = (_Float16)acc[j];
    }
  }
}

// ============================================================================
// K_C: projection GEMM + un-roll. Packed weight fragments (contiguous loads);
// wave-private LDS staging -> float4 stores (zero barriers).
// ============================================================================
__global__ __launch_bounds__(256, 6)
void proj_gemm(const _Float16* __restrict__ O, const _Float16* __restrict__ ppk,
               const float* __restrict__ proj_b, float* __restrict__ out,
               const int b_off) {
  __shared__ float ls[4][16][100];  // 25.6 KB, wave-private slabs
  const int pid = ((int)blockIdx.x & 7) * 256 + ((int)blockIdx.x >> 3);
  const int rw0 = (pid & 3) * 64;
  const int rh = (pid >> 2) & (RES - 1);
  const int bb = pid >> 10;
  const int tid = threadIdx.x;
  const int wv = tid >> 6, lane = tid & 63;
  const int ln = lane & 15, quad = lane >> 4;
  const int py0 = (bb * RES + rh) * RES + rw0 + wv * 16;

  half8 af[6];
#pragma unroll
  for (int k = 0; k < 6; ++k)
    af[k] = *(const half8*)(O + (size_t)(py0 + ln) * 192 + k * 32 + quad * 8);

  const int h = (rh + 4) & (RES - 1);
  const size_t outb =
      ((size_t)(b_off + bb) * 192) * (RES * RES) + (size_t)h * RES;
  for (int hh = 0; hh < 2; ++hh) {  // two 96-col halves
#pragma unroll
    for (int i = 0; i < 6; ++i) {
      const int nt = hh * 6 + i;
      const _Float16* bp = ppk + (size_t)nt * 3072 + lane * 8;
      floatx4 acc = {0.f, 0.f, 0.f, 0.f};
#pragma unroll
      for (int k = 0; k < 6; ++k) {
        const half8 bf = *(const half8*)(bp + k * 512);
        acc = __builtin_amdgcn_mfma_f32_16x16x32_f16(af[k], bf, acc, 0, 0, 0);
      }
      const float bias = proj_b[nt * 16 + ln];
#pragma unroll
      for (int j = 0; j < 4; ++j)
        ls[wv][quad * 4 + j][i * 16 + ln] = acc[j] + bias;
    }
    // wave-synchronous LDS->global, fully coalesced
#pragma unroll
    for (int s = 0; s < 6; ++s) {
      const int idx = lane + s * 64;           // 0..383
      const int cl = idx >> 2, g = idx & 3;
      float4 v;
      v.x = ls[wv][g * 4 + 0][cl];
      v.y = ls[wv][g * 4 + 1][cl];
      v.z = ls[wv][g * 4 + 2][cl];
      v.w = ls[wv][g * 4 + 3][cl];
      const int c = hh * 96 + cl;
      const int wout = (rw0 + wv * 16 + g * 4 + 4) & (RES - 1);
      *reinterpret_cast<float4*>(out + outb + (size_t)c * (RES * RES) + wout) = v;
    }
  }
}

// ============================================================================
// Fallback: fused single-kernel path (packed weights). Only if ws too small.
// ============================================================================
__global__ __launch_bounds__(512, 6)
void win_attn_fused(const float* __restrict__ x,
                    const _Float16* __restrict__ qpk,
                    const float* __restrict__ qkv_b,
                    const _Float16* __restrict__ ppk,
                    const float* __restrict__ proj_b,
                    float* __restrict__ out) {
  __shared__ _Float16 xs[64][200];
  __shared__ _Float16 qB[64][40];
  __shared__ _Float16 kB[64][40];
  __shared__ _Float16 vT[32][72];
  __shared__ _Float16 st[64][80];
  __shared__ float rowred[64];

  const int wid = ((int)blockIdx.x & 7) * 512 + ((int)blockIdx.x >> 3);
  const int b = wid >> 10, wh = (wid >> 5) & 31, ww = wid & 31;
  const int wv = threadIdx.x >> 6;
  const int lane = threadIdx.x & 63;
  const int ln = lane & 15;
  const int quad = lane >> 4;
  const int mt = wv >> 1, ng = wv & 1;

#pragma unroll
  for (int t = 0; t < 3; ++t) {
    const int f = threadIdx.x + t * 512;
    const int c2 = (f & 31) + 32 * (f >> 9);
    const int tg = (f >> 5) & 15;
    const int r = tg >> 1;
    const int cw = (tg & 1) * 4;
    const int h = (wh * 8 + r + 4) & (RES - 1);
    const int w0 = (ww * 8 + cw + 4) & (RES - 1);
    const size_t base = (((size_t)b * 192 + c2 * 2) * RES + h) * RES + w0;
    const float4 va = *reinterpret_cast<const float4*>(x + base);
    const float4 vb = *reinterpret_cast<const float4*>(x + base + (size_t)RES * RES);
    const int tok = tg * 4;
    half2v p;
    p[0] = (_Float16)va.x; p[1] = (_Float16)vb.x;
    *(half2v*)&xs[tok + 0][c2 * 2] = p;
    p[0] = (_Float16)va.y; p[1] = (_Float16)vb.y;
    *(half2v*)&xs[tok + 1][c2 * 2] = p;
    p[0] = (_Float16)va.z; p[1] = (_Float16)vb.z;
    *(half2v*)&xs[tok + 2][c2 * 2] = p;
    p[0] = (_Float16)va.w; p[1] = (_Float16)vb.w;
    *(half2v*)&xs[tok + 3][c2 * 2] = p;
  }
  __syncthreads();

  floatx4 acc6[6];
#pragma unroll
  for (int i = 0; i < 6; ++i) acc6[i] = (floatx4){0.f, 0.f, 0.f, 0.f};

  for (int hd = 0; hd < 6; ++hd) {
    {
      int colb[3];
#pragma unroll
      for (int i = 0; i < 3; ++i) {
        const int nt = ng * 3 + i;
        colb[i] = (nt >> 1) * 192 + hd * 32 + (nt & 1) * 16;
      }
      floatx4 acc[3];
#pragma unroll
      for (int i = 0; i < 3; ++i) acc[i] = (floatx4){0.f, 0.f, 0.f, 0.f};
#pragma unroll
      for (int k = 0; k < 6; ++k) {
        const half8 af = *(const half8*)&xs[mt * 16 + ln][k * 32 + quad * 8];
#pragma unroll
        for (int i = 0; i < 3; ++i) {
          const half8 bf = *(const half8*)(qpk +
              (size_t)(colb[i] >> 4) * 3072 + k * 512 + lane * 8);
          acc[i] = __builtin_amdgcn_mfma_f32_16x16x32_f16(af, bf, acc[i], 0, 0, 0);
        }
      }
#pragma unroll
      for (int i = 0; i < 3; ++i) {
        const int nt = ng * 3 + i;
        const int sec = nt >> 1;
        const float bias = qkv_b[colb[i] + ln];
        const int tok0 = mt * 16 + quad * 4;
        const int d = (nt & 1) * 16 + ln;
        if (sec == 0) {
#pragma unroll
          for (int j = 0; j < 4; ++j)
            qB[tok0 + j][d] = (_Float16)((acc[i][j] + bias) * SCALE_);
        } else if (sec == 1) {
#pragma unroll
          for (int j = 0; j < 4; ++j)
            kB[tok0 + j][d] = (_Float16)(acc[i][j] + bias);
        } else {
#pragma unroll
          for (int j = 0; j < 4; ++j)
            vT[d][tok0 + j] = (_Float16)(acc[i][j] + bias);
        }
      }
    }
    __syncthreads();

#pragma unroll
    for (int i = 0; i < 2; ++i) {
      const int t = wv * 2 + i;
      const int smt = t >> 2, snt = t & 3;
      const half8 aq = *(const half8*)&qB[smt * 16 + ln][quad * 8];
      const half8 bk = *(const half8*)&kB[snt * 16 + ln][quad * 8];
      floatx4 acc = {0.f, 0.f, 0.f, 0.f};
      acc = __builtin_amdgcn_mfma_f32_16x16x32_f16(aq, bk, acc, 0, 0, 0);
      const int r0 = smt * 16 + quad * 4;
#pragma unroll
      for (int j = 0; j < 4; ++j)
        st[r0 + j][snt * 16 + ln] = (_Float16)acc[j];
    }
    __syncthreads();

    {
      const int row = threadIdx.x >> 3;
      const int sl = threadIdx.x & 7;
      const half8 hv = *(const half8*)&st[row][sl * 8];
      float m = -3.0e38f;
#pragma unroll
      for (int j = 0; j < 8; ++j) m = fmaxf(m, (float)hv[j]);
      m = fmaxf(m, __shfl_xor(m, 1));
      m = fmaxf(m, __shfl_xor(m, 2));
      m = fmaxf(m, __shfl_xor(m, 4));
      float s = 0.f;
      half8 ev;
#pragma unroll
      for (int j = 0; j < 8; ++j) {
        const float e = __expf((float)hv[j] - m);
        s += e;
        ev[j] = (_Float16)e;
      }
      *(half8*)&st[row][sl * 8] = ev;
      s += __shfl_xor(s, 1);
      s += __shfl_xor(s, 2);
      s += __shfl_xor(s, 4);
      if (sl == 0) rowred[row] = 1.0f / s;
    }
    __syncthreads();

    {
      const int pmt = wv >> 1, pnt = wv & 1;
      floatx4 acc = {0.f, 0.f, 0.f, 0.f};
#pragma unroll
      for (int ks = 0; ks < 2; ++ks) {
        const half8 ap = *(const half8*)&st[pmt * 16 + ln][ks * 32 + quad * 8];
        const half8 bvv = *(const half8*)&vT[pnt * 16 + ln][ks * 32 + quad * 8];
        acc = __builtin_amdgcn_mfma_f32_16x16x32_f16(ap, bvv, acc, 0, 0, 0);
      }
      const int tok0 = pmt * 16 + quad * 4;
      const int d = pnt * 16 + ln;
#pragma unroll
      for (int j = 0; j < 4; ++j)
        qB[tok0 + j][d] = (_Float16)(acc[j] * rowred[tok0 + j]);
    }
    __syncthreads();

    {
      const half8 af = *(const half8*)&qB[mt * 16 + ln][quad * 8];
#pragma unroll
      for (int i = 0; i < 6; ++i) {
        const int nt = ng * 6 + i;
        const half8 bf = *(const half8*)(ppk +
            (size_t)nt * 3072 + hd * 512 + lane * 8);
        acc6[i] = __builtin_amdgcn_mfma_f32_16x16x32_f16(af, bf, acc6[i], 0, 0, 0);
      }
    }
    __syncthreads();
  }

  {
#pragma unroll
    for (int i = 0; i < 6; ++i) {
      const int c = (ng * 6 + i) * 16 + ln;
      const float bias = proj_b[c];
      const int tok0 = mt * 16 + quad * 4;
      const int r = tok0 >> 3, cw = tok0 & 7;
      const int h = (wh * 8 + r + 4) & (RES - 1);
      const int w0 = (ww * 8 + cw + 4) & (RES - 1);
      float4 vv;
      vv.x = acc6[i][0] + bias;
      vv.y = acc6[i][1] + bias;
      vv.z = acc6[i][2] + bias;
      vv.w = acc6[i][3] + bias;
      *reinterpret_cast<float4*>(
          out + (((size_t)b * 192 + c) * RES + h) * RES + w0) = vv;
    }
  }
}

extern "C" void kernel_launch(void* const* d_in, const int* in_sizes, int n_in,
                              void* d_out, int out_size, void* d_ws, size_t ws_size,
                              hipStream_t stream) {
  (void)in_sizes; (void)n_in; (void)out_size;
  const float* x      = (const float*)d_in[0];
  const float* qkv_w  = (const float*)d_in[1];
  const float* qkv_b  = (const float*)d_in[2];
  const float* proj_w = (const float*)d_in[3];
  const float* proj_b = (const float*)d_in[4];
  float* out = (float*)d_out;

  _Float16* qpk = (_Float16*)d_ws;            // 110592 halfs
  _Float16* ppk = qpk + QPK_HALFS;            //  36864 halfs

  prep_pack<<<72, 256, 0, stream>>>(qkv_w, proj_w, qpk, ppk);

  if (ws_size >= WT_BYTES + QK_BYTES + V_BYTES + O_BYTES) {
    _Float16* qk  = (_Float16*)((char*)d_ws + WT_BYTES);
    _Float16* vpl = (_Float16*)((char*)d_ws + WT_BYTES + QK_BYTES);
    _Float16* Obuf = (_Float16*)((char*)d_ws + WT_BYTES + QK_BYTES + V_BYTES);
    for (int c = 0; c < 2; ++c) {
      const int b_off = c * 2;  // two batches per chunk
      qkv_gemm<<<2048, 512, 0, stream>>>(x, qpk, qkv_b, qk, vpl, b_off);
      win_attn<<<dim3(2048, 6), 64, 0, stream>>>(qk, vpl, Obuf);
      proj_gemm<<<2048, 256, 0, stream>>>(Obuf, ppk, proj_b, out, b_off);
    }
  } else {
    win_attn_fused<<<4096, 512, 0, stream>>>(x, qpk, qkv_b, ppk, proj_b, out);
  }
}

// Round 6
// 625.721 us; speedup vs baseline: 1.7395x; 1.3166x over previous
//
#include <hip/hip_runtime.h>

typedef _Float16 half8 __attribute__((ext_vector_type(8)));
typedef _Float16 half4v __attribute__((ext_vector_type(4)));
typedef _Float16 half2v __attribute__((ext_vector_type(2)));
typedef float floatx4 __attribute__((ext_vector_type(4)));

namespace {
constexpr int RES = 256;
constexpr float SCALE_ = 0.17677669529663687f;  // 1/sqrt(32)
// Packed-fragment weights: qkv 36 ntiles, proj 12 ntiles; each ntile = 6
// k-frags x 64 lanes x 8 halfs.
constexpr int QPK_HALFS = 36 * 6 * 64 * 8;      // 110592
constexpr int PPK_HALFS = 12 * 6 * 64 * 8;      //  36864
constexpr size_t WT_BYTES = (QPK_HALFS + PPK_HALFS) * 2;  // 294912
constexpr size_t NPX = 131072;                  // pixels per 2-batch chunk
constexpr size_t QK_BYTES = NPX * 384 * 2;      // 100,663,296
constexpr size_t V_BYTES  = NPX * 192 * 2;      //  50,331,648
}

// ---- prep: pack weights into MFMA B-fragment order (fp16).
// pk[((nt*6 + k)*64 + lane)*8 + e] = W[(k*32 + (lane>>4)*8 + e)*ncol + nt*16 + (lane&15)]
__global__ void prep_pack(const float* __restrict__ qkv_w,
                          const float* __restrict__ proj_w,
                          _Float16* __restrict__ qpk,
                          _Float16* __restrict__ ppk) {
  const int idx = blockIdx.x * 256 + threadIdx.x;  // 0..18431
  const float* W;
  _Float16* dst;
  int ncol, base;
  if (idx < 13824) {            // 36*6*64
    W = qkv_w; dst = qpk; ncol = 576; base = idx;
  } else {
    W = proj_w; dst = ppk; ncol = 192; base = idx - 13824;
  }
  const int lane = base & 63;
  const int kk = (base >> 6) % 6;
  const int nt = base / 384;
  const int col = nt * 16 + (lane & 15);
  const int krow = kk * 32 + (lane >> 4) * 8;
  half8 v;
#pragma unroll
  for (int e = 0; e < 8; ++e) v[e] = (_Float16)W[(size_t)(krow + e) * ncol + col];
  *(half8*)(dst + (size_t)base * 8) = v;
}

// ============================================================================
// K_A: QKV GEMM, M=128 (128 w-contiguous pixels per block), 8 waves.
// Each wave owns 2 m-tiles: every 1-KB weight-fragment load feeds 2 MFMAs
// (halves per-pixel L2 weight traffic vs round 5). All global loads/stores
// are wide contiguous segments. Outputs (rolled py order):
//   qk[py][384] fp16 (q pre-scaled | k), vpl[d][py] fp16 (V channel-planar).
// ============================================================================
__global__ __launch_bounds__(512, 4)
void qkv_gemm(const float* __restrict__ x, const _Float16* __restrict__ qpk,
              const float* __restrict__ qkv_b, _Float16* __restrict__ qk,
              _Float16* __restrict__ vpl, const int b_off) {
  __shared__ _Float16 pool[26112];  // 52.2 KB: xs[128][200] -> staging buffers
  const int pid = blockIdx.x;
  const int w0 = (pid & 1) * 128;
  const int h = (pid >> 1) & (RES - 1);
  const int bb = pid >> 9;
  const int tid = threadIdx.x;

  // stage x -> pool[px][c]; per wave-load: 4 planes x 512 B contiguous.
#pragma unroll
  for (int t = 0; t < 6; ++t) {
    const int idx = tid + t * 512;          // 0..3071
    const int w4 = idx & 31;                // float4 group (4 px along w)
    const int c2 = idx >> 5;                // plane pair 0..95
    const size_t base =
        (((size_t)(b_off + bb) * 192 + c2 * 2) * RES + h) * RES + w0 + w4 * 4;
    const float4 va = *reinterpret_cast<const float4*>(x + base);
    const float4 vb = *reinterpret_cast<const float4*>(x + base + (size_t)RES * RES);
    half2v p;
    p[0] = (_Float16)va.x; p[1] = (_Float16)vb.x;
    *(half2v*)&pool[(w4 * 4 + 0) * 200 + c2 * 2] = p;
    p[0] = (_Float16)va.y; p[1] = (_Float16)vb.y;
    *(half2v*)&pool[(w4 * 4 + 1) * 200 + c2 * 2] = p;
    p[0] = (_Float16)va.z; p[1] = (_Float16)vb.z;
    *(half2v*)&pool[(w4 * 4 + 2) * 200 + c2 * 2] = p;
    p[0] = (_Float16)va.w; p[1] = (_Float16)vb.w;
    *(half2v*)&pool[(w4 * 4 + 3) * 200 + c2 * 2] = p;
  }
  __syncthreads();

  const int wv = tid >> 6, lane = tid & 63;
  const int ln = lane & 15, quad = lane >> 4;
  const int mp = wv >> 1, hf = wv & 1;  // wave: 32-px stripe x 6-ntile half

  half8 af[2][6];
#pragma unroll
  for (int mm = 0; mm < 2; ++mm)
#pragma unroll
    for (int k = 0; k < 6; ++k)
      af[mm][k] =
          *(const half8*)&pool[(mp * 32 + mm * 16 + ln) * 200 + k * 32 + quad * 8];
  __syncthreads();  // xs dead; pool becomes the output staging buffer

  const int rh = (h + RES - 4) & (RES - 1);
  const int rowbase = (bb * RES + rh) * RES;

  for (int cc = 0; cc < 3; ++cc) {  // col sections: q, k, v
#pragma unroll
    for (int i = 0; i < 6; ++i) {
      const int ntl = hf * 6 + i;                    // local 16-col tile 0..11
      const int ntg = cc * 12 + ntl;                 // global tile
      const _Float16* bp = qpk + (size_t)ntg * 3072 + lane * 8;
      floatx4 acc0 = {0.f, 0.f, 0.f, 0.f};
      floatx4 acc1 = {0.f, 0.f, 0.f, 0.f};
#pragma unroll
      for (int k = 0; k < 6; ++k) {
        const half8 bf = *(const half8*)(bp + k * 512);  // 1 KB contig/wave
        acc0 = __builtin_amdgcn_mfma_f32_16x16x32_f16(af[0][k], bf, acc0, 0, 0, 0);
        acc1 = __builtin_amdgcn_mfma_f32_16x16x32_f16(af[1][k], bf, acc1, 0, 0, 0);
      }
      const float bias = qkv_b[cc * 192 + ntl * 16 + ln];
      const float scl = (cc == 0) ? SCALE_ : 1.0f;
      const int tok0 = mp * 32 + quad * 4;
      if (cc < 2) {
#pragma unroll
        for (int j = 0; j < 4; ++j) {
          pool[(tok0 + j) * 200 + ntl * 16 + ln] =
              (_Float16)((acc0[j] + bias) * scl);
          pool[(tok0 + 16 + j) * 200 + ntl * 16 + ln] =
              (_Float16)((acc1[j] + bias) * scl);
        }
      } else {
        half4v p0, p1;
#pragma unroll
        for (int j = 0; j < 4; ++j) {
          p0[j] = (_Float16)(acc0[j] + bias);
          p1[j] = (_Float16)(acc1[j] + bias);
        }
        *(half4v*)&pool[(ntl * 16 + ln) * 132 + tok0] = p0;       // [d][px]
        *(half4v*)&pool[(ntl * 16 + ln) * 132 + tok0 + 16] = p1;
      }
    }
    __syncthreads();
    if (cc < 2) {
      // 128 px x 384 B contiguous rows (192-half halves)
#pragma unroll
      for (int p = 0; p < 6; ++p) {
        const int idx = tid + p * 512;            // 0..3071
        const int px = idx / 24, off = idx - px * 24;
        const half8 v = *(const half8*)&pool[px * 200 + off * 8];
        const int rw = (w0 + px + RES - 4) & (RES - 1);
        *(half8*)&qk[(size_t)(rowbase + rw) * 384 + cc * 192 + off * 8] = v;
      }
    } else {
      // 192 d-planes x 256 B contiguous runs
#pragma unroll
      for (int p = 0; p < 12; ++p) {
        const int idx = tid + p * 512;            // 0..6143
        const int d = idx >> 5, g4 = idx & 31;
        const half4v v = *(const half4v*)&pool[d * 132 + g4 * 4];
        const int rw = (w0 + g4 * 4 + RES - 4) & (RES - 1);
        *(half4v*)&vpl[(size_t)d * NPX + rowbase + rw] = v;
      }
    }
    __syncthreads();
  }
}

// ============================================================================
// K_B: fused window attention + projection. Block = 1 window, 6 waves
// (wave = head). Swapped QK^T (S = mfma(K,Q)) puts each q-row in one lane ->
// softmax via 2 shfl_xor; P re-fragmented for PV through a wave-private
// 2.3-KB LDS slab (in-order DS, no barrier). O_hd -> os LDS; ONE barrier;
// proj from LDS A-frags + packed ppk B-frags; f32 staged per wave; 8-B/lane
// 32-B-sector out stores. O never touches global memory.
// ============================================================================
__global__ __launch_bounds__(384, 3)
void attn_proj(const _Float16* __restrict__ qk, const _Float16* __restrict__ vpl,
               const _Float16* __restrict__ ppk, const float* __restrict__ proj_b,
               float* __restrict__ out, const int b_off) {
  __shared__ _Float16 os_[64][200];  // O [px][c], 25.6 KB
  __shared__ float lsx[6][1056];     // per-wave: exch slab (attn) / f32 out stage
  const int bid = blockIdx.x;
  const int wid = (bid & 7) * 256 + (bid >> 3);  // XCD-chunked swizzle (2048%8==0)
  const int bb = wid >> 10, wh = (wid >> 5) & 31, ww = wid & 31;
  const int wv = threadIdx.x >> 6, lane = threadIdx.x & 63;
  const int ln = lane & 15, quad = lane >> 4;
  const int hd = wv;
  const int base = (bb * RES + wh * 8) * RES + ww * 8;  // py of token 0
  float* ls = lsx[wv];
  _Float16* slab = (_Float16*)ls;   // 16 x 72 halfs, wave-private

  // ---- q/k fragments (token t = s*16+ln -> py = p0 + s*512)
  const int p0 = base + (ln >> 3) * RES + (ln & 7);
  const _Float16* qp = qk + (size_t)p0 * 384 + hd * 32 + quad * 8;
  half8 qf[4], kf[4];
#pragma unroll
  for (int s = 0; s < 4; ++s) {
    qf[s] = *(const half8*)(qp + (size_t)s * (512 * 384));
    kf[s] = *(const half8*)(qp + (size_t)s * (512 * 384) + 192);
  }
  // V B-fragments from planar layout: B[k=ktok][n=d]
  half8 bv[2][2];
#pragma unroll
  for (int pnt = 0; pnt < 2; ++pnt)
#pragma unroll
    for (int ks = 0; ks < 2; ++ks)
      bv[pnt][ks] = *(const half8*)(vpl +
          (size_t)(hd * 32 + pnt * 16 + ln) * NPX + base + (ks * 4 + quad) * RES);

  // ---- attention, one 16-q-column tile at a time (swapped-operand QK^T)
#pragma unroll
  for (int qt = 0; qt < 4; ++qt) {
    floatx4 sc[4];
#pragma unroll
    for (int kt = 0; kt < 4; ++kt) {
      floatx4 z = {0.f, 0.f, 0.f, 0.f};
      // S[ktok][q]: lane holds q = qt*16+ln, ktok = kt*16 + quad*4 + j
      sc[kt] = __builtin_amdgcn_mfma_f32_16x16x32_f16(kf[kt], qf[qt], z, 0, 0, 0);
    }
    float m = -3.0e38f;
#pragma unroll
    for (int kt = 0; kt < 4; ++kt)
#pragma unroll
      for (int j = 0; j < 4; ++j) m = fmaxf(m, sc[kt][j]);
    m = fmaxf(m, __shfl_xor(m, 16));
    m = fmaxf(m, __shfl_xor(m, 32));
    float sum = 0.f;
    float pe[4][4];
#pragma unroll
    for (int kt = 0; kt < 4; ++kt)
#pragma unroll
      for (int j = 0; j < 4; ++j) {
        pe[kt][j] = __expf(sc[kt][j] - m);
        sum += pe[kt][j];
      }
    sum += __shfl_xor(sum, 16);
    sum += __shfl_xor(sum, 32);
    const float inv = 1.0f / sum;
    // P (pre-divided) -> slab[q-local][ktok]; wave-synchronous exchange
#pragma unroll
    for (int kt = 0; kt < 4; ++kt) {
      half4v h4;
#pragma unroll
      for (int j = 0; j < 4; ++j) h4[j] = (_Float16)(pe[kt][j] * inv);
      *(half4v*)&slab[ln * 72 + kt * 16 + quad * 4] = h4;
    }
    const half8 pa0 = *(const half8*)&slab[ln * 72 + quad * 8];
    const half8 pa1 = *(const half8*)&slab[ln * 72 + 32 + quad * 8];
    floatx4 aO0 = {0.f, 0.f, 0.f, 0.f};
    floatx4 aO1 = {0.f, 0.f, 0.f, 0.f};
    aO0 = __builtin_amdgcn_mfma_f32_16x16x32_f16(pa0, bv[0][0], aO0, 0, 0, 0);
    aO0 = __builtin_amdgcn_mfma_f32_16x16x32_f16(pa1, bv[0][1], aO0, 0, 0, 0);
    aO1 = __builtin_amdgcn_mfma_f32_16x16x32_f16(pa0, bv[1][0], aO1, 0, 0, 0);
    aO1 = __builtin_amdgcn_mfma_f32_16x16x32_f16(pa1, bv[1][1], aO1, 0, 0, 0);
#pragma unroll
    for (int j = 0; j < 4; ++j) {
      os_[qt * 16 + quad * 4 + j][hd * 32 + ln] = (_Float16)aO0[j];
      os_[qt * 16 + quad * 4 + j][hd * 32 + 16 + ln] = (_Float16)aO1[j];
    }
  }
  __syncthreads();

  // ---- projection: wave wv does ntiles {wv, wv+6}; K=192 from os LDS.
  const int b = b_off + bb;
#pragma unroll
  for (int t = 0; t < 2; ++t) {
    const int nt = wv + t * 6;
    const _Float16* bp = ppk + (size_t)nt * 3072 + lane * 8;
    const float bias = proj_b[nt * 16 + ln];
#pragma unroll
    for (int mt = 0; mt < 4; ++mt) {
      floatx4 acc = {0.f, 0.f, 0.f, 0.f};
#pragma unroll
      for (int k = 0; k < 6; ++k) {
        const half8 a = *(const half8*)&os_[mt * 16 + ln][k * 32 + quad * 8];
        const half8 bf = *(const half8*)(bp + k * 512);
        acc = __builtin_amdgcn_mfma_f32_16x16x32_f16(a, bf, acc, 0, 0, 0);
      }
#pragma unroll
      for (int j = 0; j < 4; ++j)
        ls[ln * 66 + mt * 16 + quad * 4 + j] = acc[j] + bias;  // [c-local][px]
    }
    // wave-synchronous store: 32-B sector runs per (c, window-row)
#pragma unroll
    for (int s = 0; s < 8; ++s) {
      const int rid = s * 16 + (lane >> 2);   // 0..127 = 16 cl x 8 rows
      const int cl = rid >> 3, r = rid & 7;
      const int cw = (lane & 3) * 2;
      const float2 v = *(const float2*)&ls[cl * 66 + r * 8 + cw];
      const int h2 = (wh * 8 + 4 + r) & (RES - 1);
      const int w2 = (ww * 8 + 4 + cw) & (RES - 1);
      *reinterpret_cast<float2*>(
          out + (((size_t)b * 192 + nt * 16 + cl) * RES + h2) * RES + w2) = v;
    }
  }
}

// ============================================================================
// Fallback: fused single-kernel path (packed weights). Only if ws too small.
// ============================================================================
__global__ __launch_bounds__(512, 6)
void win_attn_fused(const float* __restrict__ x,
                    const _Float16* __restrict__ qpk,
                    const float* __restrict__ qkv_b,
                    const _Float16* __restrict__ ppk,
                    const float* __restrict__ proj_b,
                    float* __restrict__ out) {
  __shared__ _Float16 xs[64][200];
  __shared__ _Float16 qB[64][40];
  __shared__ _Float16 kB[64][40];
  __shared__ _Float16 vT[32][72];
  __shared__ _Float16 st[64][80];
  __shared__ float rowred[64];

  const int wid = ((int)blockIdx.x & 7) * 512 + ((int)blockIdx.x >> 3);
  const int b = wid >> 10, wh = (wid >> 5) & 31, ww = wid & 31;
  const int wv = threadIdx.x >> 6;
  const int lane = threadIdx.x & 63;
  const int ln = lane & 15;
  const int quad = lane >> 4;
  const int mt = wv >> 1, ng = wv & 1;

#pragma unroll
  for (int t = 0; t < 3; ++t) {
    const int f = threadIdx.x + t * 512;
    const int c2 = (f & 31) + 32 * (f >> 9);
    const int tg = (f >> 5) & 15;
    const int r = tg >> 1;
    const int cw = (tg & 1) * 4;
    const int h = (wh * 8 + r + 4) & (RES - 1);
    const int w0 = (ww * 8 + cw + 4) & (RES - 1);
    const size_t base = (((size_t)b * 192 + c2 * 2) * RES + h) * RES + w0;
    const float4 va = *reinterpret_cast<const float4*>(x + base);
    const float4 vb = *reinterpret_cast<const float4*>(x + base + (size_t)RES * RES);
    const int tok = tg * 4;
    half2v p;
    p[0] = (_Float16)va.x; p[1] = (_Float16)vb.x;
    *(half2v*)&xs[tok + 0][c2 * 2] = p;
    p[0] = (_Float16)va.y; p[1] = (_Float16)vb.y;
    *(half2v*)&xs[tok + 1][c2 * 2] = p;
    p[0] = (_Float16)va.z; p[1] = (_Float16)vb.z;
    *(half2v*)&xs[tok + 2][c2 * 2] = p;
    p[0] = (_Float16)va.w; p[1] = (_Float16)vb.w;
    *(half2v*)&xs[tok + 3][c2 * 2] = p;
  }
  __syncthreads();

  floatx4 acc6[6];
#pragma unroll
  for (int i = 0; i < 6; ++i) acc6[i] = (floatx4){0.f, 0.f, 0.f, 0.f};

  for (int hd = 0; hd < 6; ++hd) {
    {
      int colb[3];
#pragma unroll
      for (int i = 0; i < 3; ++i) {
        const int nt = ng * 3 + i;
        colb[i] = (nt >> 1) * 192 + hd * 32 + (nt & 1) * 16;
      }
      floatx4 acc[3];
#pragma unroll
      for (int i = 0; i < 3; ++i) acc[i] = (floatx4){0.f, 0.f, 0.f, 0.f};
#pragma unroll
      for (int k = 0; k < 6; ++k) {
        const half8 af = *(const half8*)&xs[mt * 16 + ln][k * 32 + quad * 8];
#pragma unroll
        for (int i = 0; i < 3; ++i) {
          const half8 bf = *(const half8*)(qpk +
              (size_t)(colb[i] >> 4) * 3072 + k * 512 + lane * 8);
          acc[i] = __builtin_amdgcn_mfma_f32_16x16x32_f16(af, bf, acc[i], 0, 0, 0);
        }
      }
#pragma unroll
      for (int i = 0; i < 3; ++i) {
        const int nt = ng * 3 + i;
        const int sec = nt >> 1;
        const float bias = qkv_b[colb[i] + ln];
        const int tok0 = mt * 16 + quad * 4;
        const int d = (nt & 1) * 16 + ln;
        if (sec == 0) {
#pragma unroll
          for (int j = 0; j < 4; ++j)
            qB[tok0 + j][d] = (_Float16)((acc[i][j] + bias) * SCALE_);
        } else if (sec == 1) {
#pragma unroll
          for (int j = 0; j < 4; ++j)
            kB[tok0 + j][d] = (_Float16)(acc[i][j] + bias);
        } else {
#pragma unroll
          for (int j = 0; j < 4; ++j)
            vT[d][tok0 + j] = (_Float16)(acc[i][j] + bias);
        }
      }
    }
    __syncthreads();

#pragma unroll
    for (int i = 0; i < 2; ++i) {
      const int t = wv * 2 + i;
      const int smt = t >> 2, snt = t & 3;
      const half8 aq = *(const half8*)&qB[smt * 16 + ln][quad * 8];
      const half8 bk = *(const half8*)&kB[snt * 16 + ln][quad * 8];
      floatx4 acc = {0.f, 0.f, 0.f, 0.f};
      acc = __builtin_amdgcn_mfma_f32_16x16x32_f16(aq, bk, acc, 0, 0, 0);
      const int r0 = smt * 16 + quad * 4;
#pragma unroll
      for (int j = 0; j < 4; ++j)
        st[r0 + j][snt * 16 + ln] = (_Float16)acc[j];
    }
    __syncthreads();

    {
      const int row = threadIdx.x >> 3;
      const int sl = threadIdx.x & 7;
      const half8 hv = *(const half8*)&st[row][sl * 8];
      float m = -3.0e38f;
#pragma unroll
      for (int j = 0; j < 8; ++j) m = fmaxf(m, (float)hv[j]);
      m = fmaxf(m, __shfl_xor(m, 1));
      m = fmaxf(m, __shfl_xor(m, 2));
      m = fmaxf(m, __shfl_xor(m, 4));
      float s = 0.f;
      half8 ev;
#pragma unroll
      for (int j = 0; j < 8; ++j) {
        const float e = __expf((float)hv[j] - m);
        s += e;
        ev[j] = (_Float16)e;
      }
      *(half8*)&st[row][sl * 8] = ev;
      s += __shfl_xor(s, 1);
      s += __shfl_xor(s, 2);
      s += __shfl_xor(s, 4);
      if (sl == 0) rowred[row] = 1.0f / s;
    }
    __syncthreads();

    {
      const int pmt = wv >> 1, pnt = wv & 1;
      floatx4 acc = {0.f, 0.f, 0.f, 0.f};
#pragma unroll
      for (int ks = 0; ks < 2; ++ks) {
        const half8 ap = *(const half8*)&st[pmt * 16 + ln][ks * 32 + quad * 8];
        const half8 bvv = *(const half8*)&vT[pnt * 16 + ln][ks * 32 + quad * 8];
        acc = __builtin_amdgcn_mfma_f32_16x16x32_f16(ap, bvv, acc, 0, 0, 0);
      }
      const int tok0 = pmt * 16 + quad * 4;
      const int d = pnt * 16 + ln;
#pragma unroll
      for (int j = 0; j < 4; ++j)
        qB[tok0 + j][d] = (_Float16)(acc[j] * rowred[tok0 + j]);
    }
    __syncthreads();

    {
      const half8 af = *(const half8*)&qB[mt * 16 + ln][quad * 8];
#pragma unroll
      for (int i = 0; i < 6; ++i) {
        const int nt = ng * 6 + i;
        const half8 bf = *(const half8*)(ppk +
            (size_t)nt * 3072 + hd * 512 + lane * 8);
        acc6[i] = __builtin_amdgcn_mfma_f32_16x16x32_f16(af, bf, acc6[i], 0, 0, 0);
      }
    }
    __syncthreads();
  }

  {
#pragma unroll
    for (int i = 0; i < 6; ++i) {
      const int c = (ng * 6 + i) * 16 + ln;
      const float bias = proj_b[c];
      const int tok0 = mt * 16 + quad * 4;
      const int r = tok0 >> 3, cw = tok0 & 7;
      const int h = (wh * 8 + r + 4) & (RES - 1);
      const int w0 = (ww * 8 + cw + 4) & (RES - 1);
      float4 vv;
      vv.x = acc6[i][0] + bias;
      vv.y = acc6[i][1] + bias;
      vv.z = acc6[i][2] + bias;
      vv.w = acc6[i][3] + bias;
      *reinterpret_cast<float4*>(
          out + (((size_t)b * 192 + c) * RES + h) * RES + w0) = vv;
    }
  }
}

extern "C" void kernel_launch(void* const* d_in, const int* in_sizes, int n_in,
                              void* d_out, int out_size, void* d_ws, size_t ws_size,
                              hipStream_t stream) {
  (void)in_sizes; (void)n_in; (void)out_size;
  const float* x      = (const float*)d_in[0];
  const float* qkv_w  = (const float*)d_in[1];
  const float* qkv_b  = (const float*)d_in[2];
  const float* proj_w = (const float*)d_in[3];
  const float* proj_b = (const float*)d_in[4];
  float* out = (float*)d_out;

  _Float16* qpk = (_Float16*)d_ws;            // 110592 halfs
  _Float16* ppk = qpk + QPK_HALFS;            //  36864 halfs

  prep_pack<<<72, 256, 0, stream>>>(qkv_w, proj_w, qpk, ppk);

  if (ws_size >= WT_BYTES + QK_BYTES + V_BYTES) {
    _Float16* qk  = (_Float16*)((char*)d_ws + WT_BYTES);
    _Float16* vpl = (_Float16*)((char*)d_ws + WT_BYTES + QK_BYTES);
    for (int c = 0; c < 2; ++c) {
      const int b_off = c * 2;  // two batches per chunk
      qkv_gemm<<<1024, 512, 0, stream>>>(x, qpk, qkv_b, qk, vpl, b_off);
      attn_proj<<<2048, 384, 0, stream>>>(qk, vpl, ppk, proj_b, out, b_off);
    }
  } else {
    win_attn_fused<<<4096, 512, 0, stream>>>(x, qpk, qkv_b, ppk, proj_b, out);
  }
}